// Round 17
// baseline (415.775 us; speedup 1.0000x reference)
//
#include <hip/hip_runtime.h>

typedef __attribute__((ext_vector_type(8))) short short8;   // 8 bf16 (MFMA A/B frag)
typedef __attribute__((ext_vector_type(4))) float f32x4;
typedef __attribute__((ext_vector_type(4))) int   i32x4;

#define SDIM 32
#define HDIM 34
#define NEXP 12
#define ACOL 256
#define SPB  128           // states per block: 5 blocks/CU resident, grid 2x residency
#define MAXROWS 320        // max padded rows = 128 + 12*15 = 308, round up
#define STGS 260           // bf16 staging stride (ushorts)

// raw barrier: waits LDS ops only, never drains global stores (T4)
#define BAR_LGKM() asm volatile("s_waitcnt lgkmcnt(0)\n\ts_barrier" ::: "memory")

// fp32 -> bf16 (round-to-nearest-ish), pack two into one dword
__device__ __forceinline__ unsigned int bpack(float lo, float hi) {
    unsigned int a = __builtin_bit_cast(unsigned int, lo);
    unsigned int b = __builtin_bit_cast(unsigned int, hi);
    return ((a + 0x8000u) >> 16) | ((b + 0x8000u) & 0xffff0000u);
}

// ---- k0: pack Wout into fragment-ordered bf16 records (R13 layout) ----
// wpack[((e*4+wv)*4+j)*64 + lane] = 8 bf16 of W[col=wv*64+j*16+(lane&15)][k=8g..8g+7]
__global__ __launch_bounds__(256) void k0_wpack(
    const float* __restrict__ Wout, uint4* __restrict__ wpack,
    unsigned int* __restrict__ w2p)
{
    const int tid = blockIdx.x * 256 + threadIdx.x;
    if (tid >= NEXP * 4 * 4 * 64) return;
    const int lane = tid & 63;
    const int j    = (tid >> 6) & 3;
    const int wvv  = (tid >> 8) & 3;
    const int e    = tid >> 10;
    const int r = lane & 15, g = lane >> 4;
    const int col = wvv * 64 + j * 16 + r;
    const float* wr = Wout + ((size_t)e * ACOL + col) * HDIM;
    uint4 q;
    q.x = bpack(wr[g*8+0], wr[g*8+1]);
    q.y = bpack(wr[g*8+2], wr[g*8+3]);
    q.z = bpack(wr[g*8+4], wr[g*8+5]);
    q.w = bpack(wr[g*8+6], wr[g*8+7]);
    wpack[tid] = q;
    if (tid < NEXP * ACOL) {                       // w2: k=32,33 per (e,col)
        const float* wr2 = Wout + (size_t)tid * HDIM;
        w2p[tid] = bpack(wr2[32], wr2[33]);
    }
}

__global__ __launch_bounds__(256, 5) void actor_kernel(
    const float* __restrict__ states,
    const int*   __restrict__ epoch_idx,
    const float* __restrict__ W1,
    const float* __restrict__ b1,
    const uint4* __restrict__ wpack,
    const unsigned int* __restrict__ w2p,
    const float* __restrict__ bout,
    const int*   __restrict__ mask,
    float*       __restrict__ out,
    int nB)
{
    // xs: 64 B/row = bf16 k0..31 in 4 16B chunks, chunk c at (c ^ ((row>>2)&3)).
    __shared__ __align__(16) unsigned int xs[MAXROWS * 16];      // 20480 B
    __shared__ unsigned int   xt[MAXROWS];                       // 1280 B (k32,33)
    __shared__ unsigned short rowid[MAXROWS];                    // 640 B
    __shared__ __align__(8) unsigned short stgb[16 * STGS];      // 8320 B bf16 staging
    __shared__ int cnt[NEXP], goff[NEXP], ntl[NEXP];
    // total ~30.9 KB -> 5 blocks/CU (20 waves)

    float* w1s = (float*)stgb;           // aliased: phases 0-1 only (4488 B)
    float* b1s = w1s + HDIM * SDIM;

    const int t  = threadIdx.x;
    const int s0 = blockIdx.x * SPB;

    // ---- phase 0 ----
    for (int i = t; i < HDIM * SDIM; i += 256) w1s[i] = W1[i];
    if (t < HDIM) b1s[t] = b1[t];
    if (t < NEXP) cnt[t] = 0;
    for (int i = t; i < MAXROWS; i += 256) rowid[i] = 0xFFFFu;

    const int  sidx  = s0 + t;
    const bool valid = (t < SPB) && (sidx < nB);
    float sr[SDIM];
    int e = 0;
    if (valid) {
        const f32x4* sp = (const f32x4*)(states + (size_t)sidx * SDIM);
        #pragma unroll
        for (int q = 0; q < SDIM / 4; ++q) {
            f32x4 v = sp[q];
            sr[4*q+0] = v[0]; sr[4*q+1] = v[1]; sr[4*q+2] = v[2]; sr[4*q+3] = v[3];
        }
        e = epoch_idx[sidx];
    }
    __syncthreads();                 // cnt zeroed, w1s staged

    int rank = 0;
    if (valid) rank = atomicAdd(&cnt[e], 1);
    __syncthreads();                 // cnt final

    if (t == 0) {
        int base = 0;
        #pragma unroll
        for (int i = 0; i < NEXP; ++i) {
            goff[i] = base;
            int nt = (cnt[i] + 15) >> 4;
            ntl[i] = nt;
            base += nt << 4;
        }
    }
    // trunk GEMV in PAIRS -> packed bf16 dwords directly (low VGPR pressure)
    unsigned d[17];
    if (valid) {
        #pragma unroll 1
        for (int h = 0; h < 17; ++h) {
            float a0 = b1s[2*h], a1 = (2*h+1 < HDIM) ? b1s[2*h+1] : 0.0f;
            const float4* wr0 = (const float4*)(w1s + (2*h) * SDIM);
            const float4* wr1 = (const float4*)(w1s + (2*h+1) * SDIM);
            #pragma unroll
            for (int q = 0; q < SDIM / 4; ++q) {
                float4 w0 = wr0[q];
                a0 = fmaf(sr[4*q+0], w0.x, a0);
                a0 = fmaf(sr[4*q+1], w0.y, a0);
                a0 = fmaf(sr[4*q+2], w0.z, a0);
                a0 = fmaf(sr[4*q+3], w0.w, a0);
            }
            if (2*h+1 < HDIM) {
                #pragma unroll
                for (int q = 0; q < SDIM / 4; ++q) {
                    float4 w1 = wr1[q];
                    a1 = fmaf(sr[4*q+0], w1.x, a1);
                    a1 = fmaf(sr[4*q+1], w1.y, a1);
                    a1 = fmaf(sr[4*q+2], w1.z, a1);
                    a1 = fmaf(sr[4*q+3], w1.w, a1);
                }
            }
            d[h] = bpack(fmaxf(a0, 0.0f), (2*h+1 < HDIM) ? fmaxf(a1, 0.0f) : 0.0f);
        }
    }
    __syncthreads();                 // goff ready; w1s reads done

    // ---- phase 2: scatter bf16 x row into sorted+padded slot (swizzled) ----
    if (valid) {
        const int slot = goff[e] + rank;
        const unsigned sw = (((unsigned)slot >> 2) & 3u) << 4;
        char* rbase = (char*)xs + slot * 64;
        #pragma unroll
        for (int c = 0; c < 4; ++c) {
            f32x4 q;
            q[0] = __builtin_bit_cast(float, d[4*c+0]);
            q[1] = __builtin_bit_cast(float, d[4*c+1]);
            q[2] = __builtin_bit_cast(float, d[4*c+2]);
            q[3] = __builtin_bit_cast(float, d[4*c+3]);
            *(f32x4*)(rbase + (((unsigned)(c * 16)) ^ sw)) = q;
        }
        xt[slot]    = d[16];
        rowid[slot] = (unsigned short)t;
    }
    __syncthreads();                 // xs/xt/rowid visible

    // ---- phase 3: MFMA + bf16 staged transpose; 2 lgkm barriers/tile ----
    const int wv   = t >> 6;
    const int lane = t & 63;
    const int r    = lane & 15;
    const int g    = lane >> 4;
    const int colbase = wv * 64 + r;
    const float NEG = -1e9f;
    const i32x4 mq = *(const i32x4*)(mask + 4 * lane);

    float* outb = out + (size_t)s0 * ACOL;

    for (int e2 = 0; e2 < NEXP; ++e2) {
        const int ntiles = ntl[e2];
        if (ntiles == 0) continue;

        // coalesced W fragments + per-lane store-side bias
        short8   bf1[4];
        unsigned w2[4];
        const uint4* wp = wpack + ((size_t)(e2 * 4 + wv) * 4) * 64 + lane;
        #pragma unroll
        for (int j = 0; j < 4; ++j) {
            bf1[j] = __builtin_bit_cast(short8, wp[j * 64]);
            w2[j]  = (g == 0) ? w2p[e2 * ACOL + colbase + j * 16] : 0u;
        }
        const f32x4 bias4 = *(const f32x4*)(bout + e2 * ACOL + 4 * lane);

        const int tb = goff[e2];
        for (int st = 0; st < ntiles; ++st) {
            const int rb  = tb + (st << 4);
            const int row = rb + r;
            const unsigned sw = (((unsigned)row >> 2) & 3u) << 4;
            const char* rp = (const char*)xs + row * 64;
            short8 a1 = *(const short8*)(rp + (((unsigned)(g * 16)) ^ sw));
            short8 a2 = __builtin_bit_cast(short8,
                          make_uint4(g == 0 ? xt[row] : 0u, 0u, 0u, 0u));

            f32x4 acc[4];
            #pragma unroll
            for (int j = 0; j < 4; ++j) {
                f32x4 a = {0.f, 0.f, 0.f, 0.f};
                a = __builtin_amdgcn_mfma_f32_16x16x32_bf16(a1, bf1[j], a, 0, 0, 0);
                short8 b2 = __builtin_bit_cast(short8,
                              make_uint4(w2[j], 0u, 0u, 0u));
                a = __builtin_amdgcn_mfma_f32_16x16x32_bf16(a2, b2, a, 0, 0, 0);
                acc[j] = a;
            }

            BAR_LGKM();   // WAR: all waves' reads of previous tile's stgb done

            #pragma unroll
            for (int j = 0; j < 4; ++j) {
                const int c = colbase + 16 * j;
                #pragma unroll
                for (int i = 0; i < 4; ++i)
                    stgb[(g * 4 + i) * STGS + c] =
                        (unsigned short)bpack(acc[j][i], 0.0f);
            }

            BAR_LGKM();   // RAW: staging visible

            // wave stores 4 full 1KB rows: bf16->f32 + bias + mask, plain dwordx4
            #pragma unroll
            for (int q = 0; q < 4; ++q) {
                const int lrow = wv * 4 + q;
                const unsigned rid = rowid[rb + lrow];
                const uint2 du = *(const uint2*)&stgb[lrow * STGS + 4 * lane];
                f32x4 v;
                v[0] = __builtin_bit_cast(float, du.x << 16)         + bias4[0];
                v[1] = __builtin_bit_cast(float, du.x & 0xffff0000u) + bias4[1];
                v[2] = __builtin_bit_cast(float, du.y << 16)         + bias4[2];
                v[3] = __builtin_bit_cast(float, du.y & 0xffff0000u) + bias4[3];
                v[0] = mq[0] ? v[0] : NEG;
                v[1] = mq[1] ? v[1] : NEG;
                v[2] = mq[2] ? v[2] : NEG;
                v[3] = mq[3] ? v[3] : NEG;
                if (rid != 0xFFFFu)
                    *(f32x4*)(outb + (size_t)rid * ACOL + 4 * lane) = v;
            }
        }
    }
}

extern "C" void kernel_launch(void* const* d_in, const int* in_sizes, int n_in,
                              void* d_out, int out_size, void* d_ws, size_t ws_size,
                              hipStream_t stream) {
    const float* states    = (const float*)d_in[0];
    const int*   epoch_idx = (const int*)  d_in[1];
    const float* W1        = (const float*)d_in[2];
    const float* b1        = (const float*)d_in[3];
    const float* Wout      = (const float*)d_in[4];
    const float* bout      = (const float*)d_in[5];
    const int*   mask      = (const int*)  d_in[6];
    float*       out       = (float*)d_out;

    const int nB   = in_sizes[0] / SDIM;
    const int grid = (nB + SPB - 1) / SPB;

    uint4*        wpack = (uint4*)d_ws;                          // 196608 B
    unsigned int* w2p   = (unsigned int*)((char*)d_ws + 196608); // 12288 B

    k0_wpack<<<48, 256, 0, stream>>>(Wout, wpack, w2p);
    actor_kernel<<<grid, 256, 0, stream>>>(states, epoch_idx, W1, b1,
                                           wpack, w2p, bout, mask, out, nB);
}

// Round 18
// 95.703 us; speedup vs baseline: 4.3444x; 4.3444x over previous
//
#include <hip/hip_runtime.h>

typedef __attribute__((ext_vector_type(8))) short short8;   // 8 bf16 (MFMA A/B frag)
typedef __attribute__((ext_vector_type(4))) float f32x4;
typedef __attribute__((ext_vector_type(4))) int   i32x4;

#define SDIM 32
#define HDIM 34
#define NEXP 12
#define ACOL 256
#define SPB  128           // states per block: grid = 2x residency (refill overlap)
#define MAXROWS 320        // max padded rows = 128 + 12*15 = 308, round up
#define STGS 260           // bf16 staging stride (ushorts)

// raw barrier: waits LDS ops only, never drains global stores (T4)
#define BAR_LGKM() asm volatile("s_waitcnt lgkmcnt(0)\n\ts_barrier" ::: "memory")

// fp32 -> bf16 (round-to-nearest-ish), pack two into one dword
__device__ __forceinline__ unsigned int bpack(float lo, float hi) {
    unsigned int a = __builtin_bit_cast(unsigned int, lo);
    unsigned int b = __builtin_bit_cast(unsigned int, hi);
    return ((a + 0x8000u) >> 16) | ((b + 0x8000u) & 0xffff0000u);
}

// ---- k0: pack Wout into fragment-ordered bf16 records (R13 layout) ----
// wpack[((e*4+wv)*4+j)*64 + lane] = 8 bf16 of W[col=wv*64+j*16+(lane&15)][k=8g..8g+7]
__global__ __launch_bounds__(256) void k0_wpack(
    const float* __restrict__ Wout, uint4* __restrict__ wpack,
    unsigned int* __restrict__ w2p)
{
    const int tid = blockIdx.x * 256 + threadIdx.x;
    if (tid >= NEXP * 4 * 4 * 64) return;
    const int lane = tid & 63;
    const int j    = (tid >> 6) & 3;
    const int wvv  = (tid >> 8) & 3;
    const int e    = tid >> 10;
    const int r = lane & 15, g = lane >> 4;
    const int col = wvv * 64 + j * 16 + r;
    const float* wr = Wout + ((size_t)e * ACOL + col) * HDIM;
    uint4 q;
    q.x = bpack(wr[g*8+0], wr[g*8+1]);
    q.y = bpack(wr[g*8+2], wr[g*8+3]);
    q.z = bpack(wr[g*8+4], wr[g*8+5]);
    q.w = bpack(wr[g*8+6], wr[g*8+7]);
    wpack[tid] = q;
    if (tid < NEXP * ACOL) {                       // w2: k=32,33 per (e,col)
        const float* wr2 = Wout + (size_t)tid * HDIM;
        w2p[tid] = bpack(wr2[32], wr2[33]);
    }
}

__global__ __launch_bounds__(256, 4) void actor_kernel(
    const float* __restrict__ states,
    const int*   __restrict__ epoch_idx,
    const float* __restrict__ W1,
    const float* __restrict__ b1,
    const uint4* __restrict__ wpack,
    const unsigned int* __restrict__ w2p,
    const float* __restrict__ bout,
    const int*   __restrict__ mask,
    float*       __restrict__ out,
    int nB)
{
    // xs: 64 B/row = bf16 k0..31 in 4 16B chunks, chunk c at (c ^ ((row>>2)&3)).
    __shared__ __align__(16) unsigned int xs[MAXROWS * 16];      // 20480 B
    __shared__ unsigned int   xt[MAXROWS];                       // 1280 B (k32,33)
    __shared__ unsigned short rowid[MAXROWS];                    // 640 B
    __shared__ __align__(8) unsigned short stgb[16 * STGS];      // 8320 B bf16 staging
    __shared__ int cnt[NEXP], goff[NEXP], ntl[NEXP];
    // total ~30.9 KB

    float* w1s = (float*)stgb;           // aliased: phases 0-1 only (4488 B)
    float* b1s = w1s + HDIM * SDIM;

    const int t  = threadIdx.x;
    const int s0 = blockIdx.x * SPB;

    // ---- phase 0 ----
    for (int i = t; i < HDIM * SDIM; i += 256) w1s[i] = W1[i];
    if (t < HDIM) b1s[t] = b1[t];
    if (t < NEXP) cnt[t] = 0;
    for (int i = t; i < MAXROWS; i += 256) rowid[i] = 0xFFFFu;

    const int  sidx  = s0 + t;
    const bool valid = (t < SPB) && (sidx < nB);
    float sr[SDIM];
    int e = 0;
    if (valid) {
        const f32x4* sp = (const f32x4*)(states + (size_t)sidx * SDIM);
        #pragma unroll
        for (int q = 0; q < SDIM / 4; ++q) {
            f32x4 v = sp[q];
            sr[4*q+0] = v[0]; sr[4*q+1] = v[1]; sr[4*q+2] = v[2]; sr[4*q+3] = v[3];
        }
        e = epoch_idx[sidx];
    }
    __syncthreads();                 // cnt zeroed, w1s staged

    int rank = 0;
    if (valid) rank = atomicAdd(&cnt[e], 1);
    __syncthreads();                 // cnt final

    if (t == 0) {
        int base = 0;
        #pragma unroll
        for (int i = 0; i < NEXP; ++i) {
            goff[i] = base;
            int nt = (cnt[i] + 15) >> 4;
            ntl[i] = nt;
            base += nt << 4;
        }
    }
    float x[HDIM];
    if (valid) {
        #pragma unroll 2
        for (int h = 0; h < HDIM; ++h) {
            float acc = b1s[h];
            const float4* wr = (const float4*)(w1s + h * SDIM);
            #pragma unroll
            for (int q = 0; q < SDIM / 4; ++q) {
                float4 wv = wr[q];
                acc = fmaf(sr[4*q+0], wv.x, acc);
                acc = fmaf(sr[4*q+1], wv.y, acc);
                acc = fmaf(sr[4*q+2], wv.z, acc);
                acc = fmaf(sr[4*q+3], wv.w, acc);
            }
            x[h] = fmaxf(acc, 0.0f);
        }
    }
    __syncthreads();                 // goff ready; w1s reads done

    // ---- phase 2: scatter bf16 x row into sorted+padded slot (swizzled) ----
    if (valid) {
        const int slot = goff[e] + rank;
        const unsigned sw = (((unsigned)slot >> 2) & 3u) << 4;
        char* rbase = (char*)xs + slot * 64;
        unsigned d[17];
        #pragma unroll
        for (int k = 0; k < 17; ++k) d[k] = bpack(x[2*k], x[2*k+1]);
        #pragma unroll
        for (int c = 0; c < 4; ++c) {
            f32x4 q;
            q[0] = __builtin_bit_cast(float, d[4*c+0]);
            q[1] = __builtin_bit_cast(float, d[4*c+1]);
            q[2] = __builtin_bit_cast(float, d[4*c+2]);
            q[3] = __builtin_bit_cast(float, d[4*c+3]);
            *(f32x4*)(rbase + (((unsigned)(c * 16)) ^ sw)) = q;
        }
        xt[slot]    = bpack(x[32], x[33]);
        rowid[slot] = (unsigned short)t;
    }
    __syncthreads();                 // xs/xt/rowid visible

    // ---- phase 3: MFMA + bf16 staged transpose; 2 lgkm barriers/tile ----
    const int wv   = t >> 6;
    const int lane = t & 63;
    const int r    = lane & 15;
    const int g    = lane >> 4;
    const int colbase = wv * 64 + r;
    const float NEG = -1e9f;
    const i32x4 mq = *(const i32x4*)(mask + 4 * lane);

    float* outb = out + (size_t)s0 * ACOL;

    for (int e2 = 0; e2 < NEXP; ++e2) {
        const int ntiles = ntl[e2];
        if (ntiles == 0) continue;

        // coalesced W fragments + per-lane store-side bias
        short8   bf1[4];
        unsigned w2[4];
        const uint4* wp = wpack + ((size_t)(e2 * 4 + wv) * 4) * 64 + lane;
        #pragma unroll
        for (int j = 0; j < 4; ++j) {
            bf1[j] = __builtin_bit_cast(short8, wp[j * 64]);
            w2[j]  = (g == 0) ? w2p[e2 * ACOL + colbase + j * 16] : 0u;
        }
        const f32x4 bias4 = *(const f32x4*)(bout + e2 * ACOL + 4 * lane);

        const int tb = goff[e2];
        for (int st = 0; st < ntiles; ++st) {
            const int rb  = tb + (st << 4);
            const int row = rb + r;
            const unsigned sw = (((unsigned)row >> 2) & 3u) << 4;
            const char* rp = (const char*)xs + row * 64;
            short8 a1 = *(const short8*)(rp + (((unsigned)(g * 16)) ^ sw));
            short8 a2 = __builtin_bit_cast(short8,
                          make_uint4(g == 0 ? xt[row] : 0u, 0u, 0u, 0u));

            f32x4 acc[4];
            #pragma unroll
            for (int j = 0; j < 4; ++j) {
                f32x4 a = {0.f, 0.f, 0.f, 0.f};
                a = __builtin_amdgcn_mfma_f32_16x16x32_bf16(a1, bf1[j], a, 0, 0, 0);
                short8 b2 = __builtin_bit_cast(short8,
                              make_uint4(w2[j], 0u, 0u, 0u));
                a = __builtin_amdgcn_mfma_f32_16x16x32_bf16(a2, b2, a, 0, 0, 0);
                acc[j] = a;
            }

            BAR_LGKM();   // WAR: all waves' reads of previous tile's stgb done

            #pragma unroll
            for (int j = 0; j < 4; ++j) {
                const int c = colbase + 16 * j;
                #pragma unroll
                for (int i = 0; i < 4; ++i)
                    stgb[(g * 4 + i) * STGS + c] =
                        (unsigned short)bpack(acc[j][i], 0.0f);
            }

            BAR_LGKM();   // RAW: staging visible

            // wave stores 4 full 1KB rows: bf16->f32 + bias + mask, plain dwordx4
            #pragma unroll
            for (int q = 0; q < 4; ++q) {
                const int lrow = wv * 4 + q;
                const unsigned rid = rowid[rb + lrow];
                const uint2 du = *(const uint2*)&stgb[lrow * STGS + 4 * lane];
                f32x4 v;
                v[0] = __builtin_bit_cast(float, du.x << 16)         + bias4[0];
                v[1] = __builtin_bit_cast(float, du.x & 0xffff0000u) + bias4[1];
                v[2] = __builtin_bit_cast(float, du.y << 16)         + bias4[2];
                v[3] = __builtin_bit_cast(float, du.y & 0xffff0000u) + bias4[3];
                v[0] = mq[0] ? v[0] : NEG;
                v[1] = mq[1] ? v[1] : NEG;
                v[2] = mq[2] ? v[2] : NEG;
                v[3] = mq[3] ? v[3] : NEG;
                if (rid != 0xFFFFu)
                    *(f32x4*)(outb + (size_t)rid * ACOL + 4 * lane) = v;
            }
        }
    }
}

extern "C" void kernel_launch(void* const* d_in, const int* in_sizes, int n_in,
                              void* d_out, int out_size, void* d_ws, size_t ws_size,
                              hipStream_t stream) {
    const float* states    = (const float*)d_in[0];
    const int*   epoch_idx = (const int*)  d_in[1];
    const float* W1        = (const float*)d_in[2];
    const float* b1        = (const float*)d_in[3];
    const float* Wout      = (const float*)d_in[4];
    const float* bout      = (const float*)d_in[5];
    const int*   mask      = (const int*)  d_in[6];
    float*       out       = (float*)d_out;

    const int nB   = in_sizes[0] / SDIM;
    const int grid = (nB + SPB - 1) / SPB;

    uint4*        wpack = (uint4*)d_ws;                          // 196608 B
    unsigned int* w2p   = (unsigned int*)((char*)d_ws + 196608); // 12288 B

    k0_wpack<<<48, 256, 0, stream>>>(Wout, wpack, w2p);
    actor_kernel<<<grid, 256, 0, stream>>>(states, epoch_idx, W1, b1,
                                           wpack, w2p, bout, mask, out, nB);
}